// Round 1
// baseline (1196.648 us; speedup 1.0000x reference)
//
#include <hip/hip_runtime.h>
#include <math.h>

// Problem: DigitCaps dynamic routing.
// B=256 batch, R=1152 routes, C=10 capsules, O=16 out-dim, I=8 in-dim, 3 iters.
//
// Strategy: never materialize u_hat (188 MB). Per iteration:
//   s_j = GEMM( X[256 x 9216], (c_ij ⊙ Wt)[9216 x 160] )   (split-K, two-phase)
//   v   = squash(s_j)  (fused into split-K reduction)
//   b_ij += mean_b <u_hat, v>   (recompute u_hat per (r, b) from W[r], x[b,r,:])

#define B_ 256
#define R_ 1152
#define C_ 10
#define O_ 16
#define I_ 8
#define N_ 160      // C*O
#define K_ 9216     // R*I
#define NSPLIT 72   // K splits of 128 each
#define KBLK 128    // K per block (2 stages of 64)
#define KC 64       // K per LDS stage

// workspace layout (float offsets); total 4,487,680 floats = 17.95 MB
#define WT_OFF   0
#define WT_SZ    (K_*N_)              // 1,474,560
#define PART_OFF (WT_OFF+WT_SZ)
#define PART_SZ  (4*NSPLIT*64*N_)     // 2,949,120
#define BIJ_OFF  (PART_OFF+PART_SZ)
#define BIJ_SZ   (R_*C_)              // 11,520
#define CIJ_OFF  (BIJ_OFF+BIJ_SZ)
#define CIJ_SZ   (R_*C_)
#define V_OFF    (CIJ_OFF+CIJ_SZ)
#define V_SZ     (B_*N_)              // 40,960

// ---------------------------------------------------------------------------
// Wt[k][n] = W[r,c,o,i] with k=r*8+i, n=c*16+o  (coalesced GEMM B-operand)
__global__ void k_transpose(const float* __restrict__ W, float* __restrict__ Wt) {
    int idx = blockIdx.x * 256 + threadIdx.x;          // grid covers exactly K_*N_
    int k = idx / N_;
    int n = idx - k * N_;
    int r = k >> 3, i = k & 7, c = n >> 4, o = n & 15;
    Wt[idx] = W[r * (C_*O_*I_) + c * (O_*I_) + o * I_ + i];
}

__global__ void k_zero(float* __restrict__ p) {
    p[blockIdx.x * 256 + threadIdx.x] = 0.0f;
}

// ---------------------------------------------------------------------------
// softmax over routes (axis 0) for one capsule column c = blockIdx.x
__global__ void k_softmax(const float* __restrict__ bij, float* __restrict__ cij) {
    const int c = blockIdx.x, tid = threadIdx.x;
    __shared__ float sm[4];
    __shared__ float ss[4];
    float vals[5];
    int cnt = 0;
    float m = -1e30f;
    for (int r = tid; r < R_; r += 256) {
        float t = bij[r * C_ + c];
        vals[cnt++] = t;
        m = fmaxf(m, t);
    }
    #pragma unroll
    for (int off = 32; off > 0; off >>= 1) m = fmaxf(m, __shfl_down(m, off));
    if ((tid & 63) == 0) sm[tid >> 6] = m;
    __syncthreads();
    m = fmaxf(fmaxf(sm[0], sm[1]), fmaxf(sm[2], sm[3]));
    float s = 0.0f;
    for (int j = 0; j < cnt; ++j) s += expf(vals[j] - m);
    #pragma unroll
    for (int off = 32; off > 0; off >>= 1) s += __shfl_down(s, off);
    if ((tid & 63) == 0) ss[tid >> 6] = s;
    __syncthreads();
    s = ss[0] + ss[1] + ss[2] + ss[3];
    float inv = 1.0f / s;
    cnt = 0;
    for (int r = tid; r < R_; r += 256) cij[r * C_ + c] = expf(vals[cnt++] - m) * inv;
}

// ---------------------------------------------------------------------------
// split-K GEMM: part[bt,ks][64x160] = X[64 rows][128 k] * (c ⊙ Wt)[128 k][160]
// grid (NSPLIT, 4), 256 threads; LDS 56.6 KB -> 2 blocks/CU
__global__ __launch_bounds__(256) void k_gemm(const float* __restrict__ X,
                                              const float* __restrict__ Wt,
                                              const float* __restrict__ cij,
                                              float* __restrict__ part) {
    __shared__ float As[KC][64];     // [k][b] 16 KB
    __shared__ float Bs[KC][N_];     // [k][n] 40 KB
    __shared__ float cs[160];        // c_ij for the 16 routes of this K-chunk
    const int tid = threadIdx.x;
    const int ks = blockIdx.x, bt = blockIdx.y;
    const int b0 = bt * 64, k0 = ks * KBLK;
    const int r0 = k0 >> 3;
    if (tid < 160) cs[tid] = cij[r0 * C_ + tid];

    float acc[4][10];
    #pragma unroll
    for (int i = 0; i < 4; ++i)
        #pragma unroll
        for (int j = 0; j < 10; ++j) acc[i][j] = 0.0f;

    const int rg = tid >> 4;   // 16 row groups x 4 rows
    const int cg = tid & 15;   // 16 col groups x 10 cols

    for (int st = 0; st < 2; ++st) {
        __syncthreads();
        const int kc = k0 + st * KC;
        // stage A (transposed): 1024 float4, 4 per thread
        #pragma unroll
        for (int j = 0; j < 4; ++j) {
            int q = j * 256 + tid;
            int bb = q >> 4, kf = q & 15;
            float4 a = *(const float4*)(X + (size_t)(b0 + bb) * K_ + kc + kf * 4);
            As[kf * 4 + 0][bb] = a.x;
            As[kf * 4 + 1][bb] = a.y;
            As[kf * 4 + 2][bb] = a.z;
            As[kf * 4 + 3][bb] = a.w;
        }
        // stage B with c-weighting: 2560 float4, 10 per thread
        #pragma unroll
        for (int j = 0; j < 10; ++j) {
            int q = j * 256 + tid;          // < 2560
            int kk = q / 40;                // 40 float4 per row
            int nf = (q - kk * 40) * 4;
            float4 w = *(const float4*)(Wt + (size_t)(kc + kk) * N_ + nf);
            float sc = cs[((st * KC + kk) >> 3) * C_ + (nf >> 4)];
            w.x *= sc; w.y *= sc; w.z *= sc; w.w *= sc;
            *(float4*)(&Bs[kk][nf]) = w;
        }
        __syncthreads();
        #pragma unroll 4
        for (int kk = 0; kk < KC; ++kk) {
            float4 a4 = *(const float4*)(&As[kk][rg * 4]);
            float av[4] = {a4.x, a4.y, a4.z, a4.w};
            float bv[10];
            #pragma unroll
            for (int j = 0; j < 10; ++j) bv[j] = Bs[kk][cg * 10 + j];
            #pragma unroll
            for (int i = 0; i < 4; ++i)
                #pragma unroll
                for (int j = 0; j < 10; ++j) acc[i][j] += av[i] * bv[j];
        }
    }
    float* P = part + (size_t)(bt * NSPLIT + ks) * (64 * N_);
    #pragma unroll
    for (int i = 0; i < 4; ++i)
        #pragma unroll
        for (int j = 0; j < 10; ++j)
            P[(rg * 4 + i) * N_ + cg * 10 + j] = acc[i][j];
}

// ---------------------------------------------------------------------------
// sum the 72 split-K partials, apply squash; 160 blocks x 256 = 40960 outputs
__global__ void k_reduce_squash(const float* __restrict__ part, float* __restrict__ out) {
    int gidx = blockIdx.x * 256 + threadIdx.x;   // < 40960
    int b = gidx / N_;
    int bt = b >> 6;
    int local = gidx - bt * (64 * N_);
    const float* p = part + (size_t)bt * NSPLIT * (64 * N_) + local;
    float s = 0.0f;
    #pragma unroll 8
    for (int ks = 0; ks < NSPLIT; ++ks) s += p[(size_t)ks * (64 * N_)];
    // squash: s^3/((1+s^2)*|s|) = s*|s|/(1+s^2)
    out[gidx] = s * fabsf(s) / (1.0f + s * s);
}

// ---------------------------------------------------------------------------
// agreement: b_ij[r,c] += (1/B) sum_b sum_o u_hat[b,r,c,o]*v[b,c,o]
// one block per route r, one thread per batch b
__global__ __launch_bounds__(256) void k_agree(const float* __restrict__ x,
                                               const float* __restrict__ W,
                                               const float* __restrict__ v,
                                               float* __restrict__ bij) {
    __shared__ float Ws[C_ * O_ * I_];   // 1280 floats, W[r] in native [c][o][i]
    const int r = blockIdx.x, tid = threadIdx.x;
    #pragma unroll
    for (int j = 0; j < 2; ++j) {
        int q = j * 256 + tid;
        if (q < 320) {
            float4 w = *(const float4*)(W + (size_t)r * 1280 + q * 4);
            *(float4*)(&Ws[q * 4]) = w;
        }
    }
    float xr[8];
    {
        float4 x0 = *(const float4*)(x + (size_t)tid * K_ + r * 8);
        float4 x1 = *(const float4*)(x + (size_t)tid * K_ + r * 8 + 4);
        xr[0] = x0.x; xr[1] = x0.y; xr[2] = x0.z; xr[3] = x0.w;
        xr[4] = x1.x; xr[5] = x1.y; xr[6] = x1.z; xr[7] = x1.w;
    }
    __syncthreads();
    float ac[10];
    #pragma unroll
    for (int c = 0; c < 10; ++c) {
        const float* vp = v + (size_t)tid * N_ + c * 16;
        float4 v0 = *(const float4*)(vp);
        float4 v1 = *(const float4*)(vp + 4);
        float4 v2 = *(const float4*)(vp + 8);
        float4 v3 = *(const float4*)(vp + 12);
        float vv[16] = {v0.x, v0.y, v0.z, v0.w, v1.x, v1.y, v1.z, v1.w,
                        v2.x, v2.y, v2.z, v2.w, v3.x, v3.y, v3.z, v3.w};
        float s = 0.0f;
        #pragma unroll
        for (int o = 0; o < 16; ++o) {
            const float* wp = &Ws[c * 128 + o * 8];
            float u = 0.0f;
            #pragma unroll
            for (int i = 0; i < 8; ++i) u += wp[i] * xr[i];
            s += u * vv[o];
        }
        ac[c] = s;
    }
    // block-wide reduction over the 256 b-threads
    const int lane = tid & 63, wv = tid >> 6;
    __shared__ float red[4][10];
    #pragma unroll
    for (int c = 0; c < 10; ++c) {
        float s = ac[c];
        #pragma unroll
        for (int off = 32; off > 0; off >>= 1) s += __shfl_down(s, off);
        if (lane == 0) red[wv][c] = s;
    }
    __syncthreads();
    if (tid < 10) {
        float s = red[0][tid] + red[1][tid] + red[2][tid] + red[3][tid];
        bij[r * C_ + tid] += s * (1.0f / B_);
    }
}

// ---------------------------------------------------------------------------
extern "C" void kernel_launch(void* const* d_in, const int* in_sizes, int n_in,
                              void* d_out, int out_size, void* d_ws, size_t ws_size,
                              hipStream_t stream) {
    const float* x = (const float*)d_in[0];   // (256, 1152, 8)
    const float* W = (const float*)d_in[1];   // (1152, 10, 16, 8)
    float* ws   = (float*)d_ws;
    float* Wt   = ws + WT_OFF;
    float* part = ws + PART_OFF;
    float* bij  = ws + BIJ_OFF;
    float* cij  = ws + CIJ_OFF;
    float* vws  = ws + V_OFF;

    k_transpose<<<(K_ * N_) / 256, 256, 0, stream>>>(W, Wt);
    k_zero<<<(R_ * C_) / 256, 256, 0, stream>>>(bij);

    for (int it = 0; it < 3; ++it) {
        k_softmax<<<C_, 256, 0, stream>>>(bij, cij);
        k_gemm<<<dim3(NSPLIT, 4), 256, 0, stream>>>(x, Wt, cij, part);
        k_reduce_squash<<<(B_ * N_) / 256, 256, 0, stream>>>(
            part, (it == 2) ? (float*)d_out : vws);
        if (it < 2) k_agree<<<R_, 256, 0, stream>>>(x, W, vws, bij);
    }
}

// Round 2
// 235.111 us; speedup vs baseline: 5.0897x; 5.0897x over previous
//
#include <hip/hip_runtime.h>
#include <math.h>

// DigitCaps dynamic routing. B=256, R=1152, C=10, O=16, I=8, 3 iters.
//
// Per iteration:
//   s_j  = GEMM( X[256 x 9216], (c_ij ⊙ Wt)[9216 x 160] )  split-K
//   v    = squash(s_j)  (fused into split-K reduction)
//   G    = Xᵀ·V  GEMM [9216x256]x[256x160]                 (agreement, part 1)
//   b_ij += (1/B) Σ_{o,i} W[r,c,o,i]·G[r*8+i, c*16+o]      (agreement, part 2)
// u_hat (188 MB) is never materialized; the old per-(r,b) agreement kernel
// spilled ~3KB/thread to scratch (925 MB writes/dispatch) — replaced by GEMM.

#define B_ 256
#define R_ 1152
#define C_ 10
#define O_ 16
#define I_ 8
#define N_ 160      // C*O
#define K_ 9216     // R*I
#define NSPLIT 72   // K splits of 128 each
#define KBLK 128
#define KC 64

// workspace layout (float offsets); G aliases part (sequential use)
#define WT_OFF   0
#define WT_SZ    (K_*N_)              // 1,474,560
#define PART_OFF (WT_OFF+WT_SZ)
#define PART_SZ  (4*NSPLIT*64*N_)     // 2,949,120  (>= K_*N_ needed for G)
#define BIJ_OFF  (PART_OFF+PART_SZ)
#define BIJ_SZ   (R_*C_)
#define CIJ_OFF  (BIJ_OFF+BIJ_SZ)
#define CIJ_SZ   (R_*C_)
#define V_OFF    (CIJ_OFF+CIJ_SZ)
#define V_SZ     (B_*N_)

// ---------------------------------------------------------------------------
__global__ void k_transpose(const float* __restrict__ W, float* __restrict__ Wt) {
    int idx = blockIdx.x * 256 + threadIdx.x;
    int k = idx / N_;
    int n = idx - k * N_;
    int r = k >> 3, i = k & 7, c = n >> 4, o = n & 15;
    Wt[idx] = W[r * (C_*O_*I_) + c * (O_*I_) + o * I_ + i];
}

__global__ void k_zero(float* __restrict__ p) {
    p[blockIdx.x * 256 + threadIdx.x] = 0.0f;
}

// ---------------------------------------------------------------------------
__global__ void k_softmax(const float* __restrict__ bij, float* __restrict__ cij) {
    const int c = blockIdx.x, tid = threadIdx.x;
    __shared__ float sm[4];
    __shared__ float ss[4];
    float vals[5];
    int cnt = 0;
    float m = -1e30f;
    for (int r = tid; r < R_; r += 256) {
        float t = bij[r * C_ + c];
        vals[cnt++] = t;
        m = fmaxf(m, t);
    }
    #pragma unroll
    for (int off = 32; off > 0; off >>= 1) m = fmaxf(m, __shfl_down(m, off));
    if ((tid & 63) == 0) sm[tid >> 6] = m;
    __syncthreads();
    m = fmaxf(fmaxf(sm[0], sm[1]), fmaxf(sm[2], sm[3]));
    float s = 0.0f;
    for (int j = 0; j < cnt; ++j) s += expf(vals[j] - m);
    #pragma unroll
    for (int off = 32; off > 0; off >>= 1) s += __shfl_down(s, off);
    if ((tid & 63) == 0) ss[tid >> 6] = s;
    __syncthreads();
    s = ss[0] + ss[1] + ss[2] + ss[3];
    float inv = 1.0f / s;
    cnt = 0;
    for (int r = tid; r < R_; r += 256) cij[r * C_ + c] = expf(vals[cnt++] - m) * inv;
}

// ---------------------------------------------------------------------------
// split-K GEMM: part[bt,ks][64x160] = X[64 rows][128 k] * (c ⊙ Wt)[128 k][160]
__global__ __launch_bounds__(256) void k_gemm(const float* __restrict__ X,
                                              const float* __restrict__ Wt,
                                              const float* __restrict__ cij,
                                              float* __restrict__ part) {
    __shared__ float As[KC][64];
    __shared__ float Bs[KC][N_];
    __shared__ float cs[160];
    const int tid = threadIdx.x;
    const int ks = blockIdx.x, bt = blockIdx.y;
    const int b0 = bt * 64, k0 = ks * KBLK;
    const int r0 = k0 >> 3;
    if (tid < 160) cs[tid] = cij[r0 * C_ + tid];

    float acc[4][10];
    #pragma unroll
    for (int i = 0; i < 4; ++i)
        #pragma unroll
        for (int j = 0; j < 10; ++j) acc[i][j] = 0.0f;

    const int rg = tid >> 4;
    const int cg = tid & 15;

    for (int st = 0; st < 2; ++st) {
        __syncthreads();
        const int kc = k0 + st * KC;
        #pragma unroll
        for (int j = 0; j < 4; ++j) {
            int q = j * 256 + tid;
            int bb = q >> 4, kf = q & 15;
            float4 a = *(const float4*)(X + (size_t)(b0 + bb) * K_ + kc + kf * 4);
            As[kf * 4 + 0][bb] = a.x;
            As[kf * 4 + 1][bb] = a.y;
            As[kf * 4 + 2][bb] = a.z;
            As[kf * 4 + 3][bb] = a.w;
        }
        #pragma unroll
        for (int j = 0; j < 10; ++j) {
            int q = j * 256 + tid;
            int kk = q / 40;
            int nf = (q - kk * 40) * 4;
            float4 w = *(const float4*)(Wt + (size_t)(kc + kk) * N_ + nf);
            float sc = cs[((st * KC + kk) >> 3) * C_ + (nf >> 4)];
            w.x *= sc; w.y *= sc; w.z *= sc; w.w *= sc;
            *(float4*)(&Bs[kk][nf]) = w;
        }
        __syncthreads();
        #pragma unroll 4
        for (int kk = 0; kk < KC; ++kk) {
            float4 a4 = *(const float4*)(&As[kk][rg * 4]);
            float av[4] = {a4.x, a4.y, a4.z, a4.w};
            float bv[10];
            #pragma unroll
            for (int j = 0; j < 10; ++j) bv[j] = Bs[kk][cg * 10 + j];
            #pragma unroll
            for (int i = 0; i < 4; ++i)
                #pragma unroll
                for (int j = 0; j < 10; ++j) acc[i][j] += av[i] * bv[j];
        }
    }
    float* P = part + (size_t)(bt * NSPLIT + ks) * (64 * N_);
    #pragma unroll
    for (int i = 0; i < 4; ++i)
        #pragma unroll
        for (int j = 0; j < 10; ++j)
            P[(rg * 4 + i) * N_ + cg * 10 + j] = acc[i][j];
}

// ---------------------------------------------------------------------------
__global__ void k_reduce_squash(const float* __restrict__ part, float* __restrict__ out) {
    int gidx = blockIdx.x * 256 + threadIdx.x;
    int b = gidx / N_;
    int bt = b >> 6;
    int local = gidx - bt * (64 * N_);
    const float* p = part + (size_t)bt * NSPLIT * (64 * N_) + local;
    float s = 0.0f;
    #pragma unroll 8
    for (int ks = 0; ks < NSPLIT; ++ks) s += p[(size_t)ks * (64 * N_)];
    out[gidx] = s * fabsf(s) / (1.0f + s * s);
}

// ---------------------------------------------------------------------------
// G[k][n] = sum_b X[b][k] * V[b][n]; grid 144 blocks of 64 k-rows x full 160 n
__global__ __launch_bounds__(256) void k_gt(const float* __restrict__ X,
                                            const float* __restrict__ V,
                                            float* __restrict__ G) {
    __shared__ float Xs[64][64];   // [b][k] 16 KB
    __shared__ float Vs[64][N_];   // [b][n] 40 KB
    const int tid = threadIdx.x;
    const int k0 = blockIdx.x * 64;
    const int rg = tid >> 4, cg = tid & 15;
    float acc[4][10];
    #pragma unroll
    for (int i = 0; i < 4; ++i)
        #pragma unroll
        for (int j = 0; j < 10; ++j) acc[i][j] = 0.0f;

    for (int bt = 0; bt < 4; ++bt) {
        __syncthreads();
        const int b0 = bt * 64;
        #pragma unroll
        for (int j = 0; j < 4; ++j) {
            int q = j * 256 + tid;
            int bb = q >> 4, kf = q & 15;
            *(float4*)(&Xs[bb][kf * 4]) =
                *(const float4*)(X + (size_t)(b0 + bb) * K_ + k0 + kf * 4);
        }
        #pragma unroll
        for (int j = 0; j < 10; ++j) {
            int q = j * 256 + tid;
            int bb = q / 40, nf = (q - bb * 40) * 4;
            *(float4*)(&Vs[bb][nf]) = *(const float4*)(V + (size_t)(b0 + bb) * N_ + nf);
        }
        __syncthreads();
        #pragma unroll 4
        for (int b = 0; b < 64; ++b) {
            float4 a4 = *(const float4*)(&Xs[b][rg * 4]);
            float av[4] = {a4.x, a4.y, a4.z, a4.w};
            float bv[10];
            #pragma unroll
            for (int j = 0; j < 10; ++j) bv[j] = Vs[b][cg * 10 + j];
            #pragma unroll
            for (int i = 0; i < 4; ++i)
                #pragma unroll
                for (int j = 0; j < 10; ++j) acc[i][j] += av[i] * bv[j];
        }
    }
    #pragma unroll
    for (int i = 0; i < 4; ++i)
        #pragma unroll
        for (int j = 0; j < 10; ++j)
            G[(size_t)(k0 + rg * 4 + i) * N_ + cg * 10 + j] = acc[i][j];
}

// ---------------------------------------------------------------------------
// b_ij[r,c] += (1/B) sum_{o,i} W[r,c,o,i] * G[r*8+i][c*16+o]; one block per r
__global__ void k_dot(const float* __restrict__ W, const float* __restrict__ G,
                      float* __restrict__ bij) {
    const int r = blockIdx.x, tid = threadIdx.x;
    __shared__ float Ws[1280];
    __shared__ float Gs[1280];
    for (int q = tid; q < 320; q += 256)
        *(float4*)(&Ws[q * 4]) = *(const float4*)(W + (size_t)r * 1280 + q * 4);
    for (int q = tid; q < 320; q += 256)
        *(float4*)(&Gs[q * 4]) = *(const float4*)(G + (size_t)r * 8 * N_ + q * 4);
    __syncthreads();
    if (tid < 160) {
        int c = tid >> 4, o = tid & 15;
        float s = 0.0f;
        #pragma unroll
        for (int i = 0; i < 8; ++i)
            s += Ws[c * 128 + o * 8 + i] * Gs[i * 160 + c * 16 + o];
        #pragma unroll
        for (int off = 8; off > 0; off >>= 1) s += __shfl_down(s, off, 16);
        if (o == 0) bij[r * C_ + c] += s * (1.0f / B_);
    }
}

// ---------------------------------------------------------------------------
extern "C" void kernel_launch(void* const* d_in, const int* in_sizes, int n_in,
                              void* d_out, int out_size, void* d_ws, size_t ws_size,
                              hipStream_t stream) {
    const float* x = (const float*)d_in[0];   // (256, 1152, 8)
    const float* W = (const float*)d_in[1];   // (1152, 10, 16, 8)
    float* ws   = (float*)d_ws;
    float* Wt   = ws + WT_OFF;
    float* part = ws + PART_OFF;
    float* G    = part;                        // aliased: part dead when G live
    float* bij  = ws + BIJ_OFF;
    float* cij  = ws + CIJ_OFF;
    float* vws  = ws + V_OFF;

    k_transpose<<<(K_ * N_) / 256, 256, 0, stream>>>(W, Wt);
    k_zero<<<(R_ * C_) / 256, 256, 0, stream>>>(bij);

    for (int it = 0; it < 3; ++it) {
        k_softmax<<<C_, 256, 0, stream>>>(bij, cij);
        k_gemm<<<dim3(NSPLIT, 4), 256, 0, stream>>>(x, Wt, cij, part);
        k_reduce_squash<<<(B_ * N_) / 256, 256, 0, stream>>>(
            part, (it == 2) ? (float*)d_out : vws);
        if (it < 2) {
            k_gt<<<K_ / 64, 256, 0, stream>>>(x, vws, G);
            k_dot<<<R_, 256, 0, stream>>>(W, G, bij);
        }
    }
}

// Round 4
// 207.366 us; speedup vs baseline: 5.7707x; 1.1338x over previous
//
#include <hip/hip_runtime.h>
#include <math.h>

// DigitCaps dynamic routing. B=256, R=1152, C=10, O=16, I=8, 3 iters.
//
// 8 launches total:
//   iter 0..2: k_gemm_f  (softmax fused; iter0 uses c=1/1152; W staged natively)
//              k_reduce_squash (72-way split-K reduce + squash -> v or d_out)
//   iter 0..1: k_gtdot   (G = X^T·V tile in registers -> LDS -> per-route dot
//                         with W -> b_ij; no G in HBM)
// u_hat (188 MB) never materialized. No Wt, no separate softmax/zero kernels.

#define B_ 256
#define R_ 1152
#define C_ 10
#define N_ 160      // C*O
#define K_ 9216     // R*I
#define NSPLIT 72   // K splits of 128
#define KC 64       // K per LDS stage (8 routes)

// workspace layout (float offsets)
#define PART_OFF 0
#define PART_SZ  (4*NSPLIT*64*N_)     // 2,949,120
#define BIJ_OFF  (PART_OFF+PART_SZ)
#define BIJ_SZ   (R_*C_)
#define V_OFF    (BIJ_OFF+BIJ_SZ)
#define V_SZ     (B_*N_)

// ---------------------------------------------------------------------------
// split-K GEMM with fused softmax: part[bt,ks][64x160] =
//   X[64 b][128 k] * (softmax_r(bij) ⊙ W)[128 k][160 n]
// grid (72, 4) x 256 threads; LDS ~57.8 KB -> 2 blocks/CU
__global__ __launch_bounds__(256) void k_gemm_f(const float* __restrict__ X,
                                                const float* __restrict__ W,
                                                const float* __restrict__ bij,
                                                float* __restrict__ part,
                                                int first) {
    __shared__ float As[KC][64];     // [k][b] 16 KB
    __shared__ float Bs[KC][N_];     // [k][n] 40 KB
    __shared__ float cs[160];        // c_ij for this block's 16 routes
    __shared__ float red[4][10];
    __shared__ float dsm[10];
    const int tid = threadIdx.x;
    const int ks = blockIdx.x, bt = blockIdx.y;
    const int b0 = bt * 64, k0 = ks * 128;
    const int r0 = ks * 16;

    // ---- fused softmax over routes (axis 0), redundant per block ----
    if (first) {
        if (tid < 160) cs[tid] = 1.0f / 1152.0f;
    } else {
        float dcol[10];
        #pragma unroll
        for (int c = 0; c < 10; ++c) dcol[c] = 0.0f;
        for (int r = tid; r < R_; r += 256) {
            #pragma unroll
            for (int c = 0; c < 10; ++c) dcol[c] += __expf(bij[r * 10 + c]);
        }
        const int lane = tid & 63, wv = tid >> 6;
        #pragma unroll
        for (int c = 0; c < 10; ++c) {
            float s = dcol[c];
            #pragma unroll
            for (int off = 32; off > 0; off >>= 1) s += __shfl_down(s, off);
            if (lane == 0) red[wv][c] = s;
        }
        __syncthreads();
        if (tid < 10) dsm[tid] = red[0][tid] + red[1][tid] + red[2][tid] + red[3][tid];
        __syncthreads();
        if (tid < 160) {
            int rr = tid / 10, cc = tid - rr * 10;
            cs[tid] = __expf(bij[(r0 + rr) * 10 + cc]) / dsm[cc];
        }
    }

    float acc[4][10];
    #pragma unroll
    for (int i = 0; i < 4; ++i)
        #pragma unroll
        for (int j = 0; j < 10; ++j) acc[i][j] = 0.0f;

    const int rg = tid >> 4;   // 16 row groups x 4 rows (b)
    const int cg = tid & 15;   // 16 col groups x 10 cols (n)

    for (int st = 0; st < 2; ++st) {
        __syncthreads();
        const int kc = k0 + st * KC;
        // stage A (transposed): 1024 float4
        #pragma unroll
        for (int j = 0; j < 4; ++j) {
            int q = j * 256 + tid;
            int bb = q >> 4, kf = q & 15;
            float4 a = *(const float4*)(X + (size_t)(b0 + bb) * K_ + kc + kf * 4);
            As[kf * 4 + 0][bb] = a.x;
            As[kf * 4 + 1][bb] = a.y;
            As[kf * 4 + 2][bb] = a.z;
            As[kf * 4 + 3][bb] = a.w;
        }
        // stage B from NATIVE W layout (contiguous 8-route slice, coalesced
        // float4 reads, scatter-transpose into Bs with c_ij scaling)
        const float* Wsl = W + (size_t)(r0 + st * 8) * 1280;
        #pragma unroll
        for (int j = 0; j < 10; ++j) {
            int q = j * 256 + tid;            // float4 index, < 2560
            int rl = q / 320;                 // local route 0..7
            int rem = q - rl * 320;
            int c = rem >> 5;                 // 0..9
            int rem2 = rem & 31;
            int o = rem2 >> 1;                // 0..15
            int i4 = rem2 & 1;                // float4 half of i
            float4 w = *(const float4*)(Wsl + (size_t)q * 4);
            float sc = cs[(st * 8 + rl) * 10 + c];
            int kk = rl * 8 + i4 * 4;
            int nn = c * 16 + o;
            Bs[kk + 0][nn] = w.x * sc;
            Bs[kk + 1][nn] = w.y * sc;
            Bs[kk + 2][nn] = w.z * sc;
            Bs[kk + 3][nn] = w.w * sc;
        }
        __syncthreads();
        #pragma unroll 4
        for (int kk = 0; kk < KC; ++kk) {
            float4 a4 = *(const float4*)(&As[kk][rg * 4]);
            float av[4] = {a4.x, a4.y, a4.z, a4.w};
            float bv[10];
            #pragma unroll
            for (int j = 0; j < 10; ++j) bv[j] = Bs[kk][cg * 10 + j];
            #pragma unroll
            for (int i = 0; i < 4; ++i)
                #pragma unroll
                for (int j = 0; j < 10; ++j) acc[i][j] += av[i] * bv[j];
        }
    }
    float* P = part + (size_t)(bt * NSPLIT + ks) * (64 * N_);
    #pragma unroll
    for (int i = 0; i < 4; ++i)
        #pragma unroll
        for (int j = 0; j < 10; ++j)
            P[(rg * 4 + i) * N_ + cg * 10 + j] = acc[i][j];
}

// ---------------------------------------------------------------------------
__global__ void k_reduce_squash(const float* __restrict__ part, float* __restrict__ out) {
    int gidx = blockIdx.x * 256 + threadIdx.x;   // < 40960
    int b = gidx / N_;
    int bt = b >> 6;
    int local = gidx - bt * (64 * N_);
    const float* p = part + (size_t)bt * NSPLIT * (64 * N_) + local;
    float s = 0.0f;
    #pragma unroll 8
    for (int ks = 0; ks < NSPLIT; ++ks) s += p[(size_t)ks * (64 * N_)];
    out[gidx] = s * fabsf(s) / (1.0f + s * s);
}

// ---------------------------------------------------------------------------
// fused agreement: per block (64 k-rows = 8 routes):
//   G[k][n] = sum_b X[b][k]*V[b][n]  (registers, 4 b-stages)
//   -> LDS -> b_ij[r,c] (+)= (1/B) sum_{o,i} W[r,c,o,i]*G[8rl+i][16c+o]
// grid 144 x 256; LDS 57 KB -> 2 blocks/CU
__global__ __launch_bounds__(256) void k_gtdot(const float* __restrict__ X,
                                               const float* __restrict__ W,
                                               const float* __restrict__ V,
                                               float* __restrict__ bij,
                                               int first) {
    __shared__ float Xs[64][64];     // [b][k] 16 KB
    __shared__ float Vs[64][164];    // [b][n] staged, then reused as G[k][n]; padded
    const int tid = threadIdx.x;
    const int k0 = blockIdx.x * 64;
    const int rg = tid >> 4, cg = tid & 15;
    float acc[4][10];
    #pragma unroll
    for (int i = 0; i < 4; ++i)
        #pragma unroll
        for (int j = 0; j < 10; ++j) acc[i][j] = 0.0f;

    for (int bt = 0; bt < 4; ++bt) {
        __syncthreads();
        const int b0 = bt * 64;
        #pragma unroll
        for (int j = 0; j < 4; ++j) {
            int q = j * 256 + tid;
            int bb = q >> 4, kf = q & 15;
            *(float4*)(&Xs[bb][kf * 4]) =
                *(const float4*)(X + (size_t)(b0 + bb) * K_ + k0 + kf * 4);
        }
        #pragma unroll
        for (int j = 0; j < 10; ++j) {
            int q = j * 256 + tid;
            int bb = q / 40, nf = (q - bb * 40) * 4;
            *(float4*)(&Vs[bb][nf]) = *(const float4*)(V + (size_t)(b0 + bb) * N_ + nf);
        }
        __syncthreads();
        #pragma unroll 4
        for (int b = 0; b < 64; ++b) {
            float4 a4 = *(const float4*)(&Xs[b][rg * 4]);
            float av[4] = {a4.x, a4.y, a4.z, a4.w};
            float bv[10];
            #pragma unroll
            for (int j = 0; j < 10; ++j) bv[j] = Vs[b][cg * 10 + j];
            #pragma unroll
            for (int i = 0; i < 4; ++i)
                #pragma unroll
                for (int j = 0; j < 10; ++j) acc[i][j] += av[i] * bv[j];
        }
    }
    // G tile -> LDS (reuse Vs)
    __syncthreads();
    #pragma unroll
    for (int i = 0; i < 4; ++i)
        #pragma unroll
        for (int j = 0; j < 10; ++j)
            Vs[rg * 4 + i][cg * 10 + j] = acc[i][j];
    __syncthreads();
    // per-route dot with W (native layout; 128 consecutive floats per (r,c))
    if (tid < 80) {
        int rl = tid / 10, c = tid - rl * 10;
        int r = (k0 >> 3) + rl;
        const float4* wp4 = (const float4*)(W + (size_t)r * 1280 + c * 128);
        float s = 0.0f;
        #pragma unroll
        for (int o = 0; o < 16; ++o) {
            float4 wa = wp4[o * 2], wb = wp4[o * 2 + 1];
            int nn = c * 16 + o, kk = rl * 8;
            s += wa.x * Vs[kk + 0][nn] + wa.y * Vs[kk + 1][nn] +
                 wa.z * Vs[kk + 2][nn] + wa.w * Vs[kk + 3][nn] +
                 wb.x * Vs[kk + 4][nn] + wb.y * Vs[kk + 5][nn] +
                 wb.z * Vs[kk + 6][nn] + wb.w * Vs[kk + 7][nn];
        }
        if (first) bij[r * 10 + c] = s * (1.0f / B_);
        else       bij[r * 10 + c] += s * (1.0f / B_);
    }
}

// ---------------------------------------------------------------------------
extern "C" void kernel_launch(void* const* d_in, const int* in_sizes, int n_in,
                              void* d_out, int out_size, void* d_ws, size_t ws_size,
                              hipStream_t stream) {
    const float* x = (const float*)d_in[0];   // (256, 1152, 8)
    const float* W = (const float*)d_in[1];   // (1152, 10, 16, 8)
    float* ws   = (float*)d_ws;
    float* part = ws + PART_OFF;
    float* bij  = ws + BIJ_OFF;
    float* vws  = ws + V_OFF;

    for (int it = 0; it < 3; ++it) {
        k_gemm_f<<<dim3(NSPLIT, 4), 256, 0, stream>>>(x, W, bij, part, it == 0);
        k_reduce_squash<<<(B_ * N_) / 256, 256, 0, stream>>>(
            part, (it == 2) ? (float*)d_out : vws);
        if (it < 2) k_gtdot<<<144, 256, 0, stream>>>(x, W, vws, bij, it == 0);
    }
}